// Round 7
// baseline (236.724 us; speedup 1.0000x reference)
//
#include <hip/hip_runtime.h>
#include <stdint.h>

#define Bn 32
#define Nn 256
#define En 512
#define Hn 8
#define Dn 64

typedef __attribute__((ext_vector_type(8))) short bf16x8;   // MFMA A/B frag (4 VGPRs)
typedef __attribute__((ext_vector_type(4))) float f32x4;    // MFMA C/D frag

__device__ __forceinline__ unsigned short f2bf(float f){
  union{float f; uint32_t i;} v; v.f = f;
  uint32_t i = v.i;
  return (unsigned short)((i + 0x7fffu + ((i>>16)&1u)) >> 16);  // RNE
}

// ---------------------------------------------------------------------------
// Generic fp32 -> bf16 conversion; n = gridDim.x*2048 elements exactly.
// ---------------------------------------------------------------------------
__global__ __launch_bounds__(256) void convert_bf16(
    const float* __restrict__ src, unsigned short* __restrict__ dst){
  size_t i = ((size_t)blockIdx.x * 256 + threadIdx.x) * 8;
  float4 a = *(const float4*)(src + i);
  float4 b = *(const float4*)(src + i + 4);
  bf16x8 p;
  p[0]=(short)f2bf(a.x); p[1]=(short)f2bf(a.y); p[2]=(short)f2bf(a.z); p[3]=(short)f2bf(a.w);
  p[4]=(short)f2bf(b.x); p[5]=(short)f2bf(b.y); p[6]=(short)f2bf(b.z); p[7]=(short)f2bf(b.w);
  *(bf16x8*)(dst + i) = p;
}

// ---------------------------------------------------------------------------
// Kernel A: qkv = x @ w_qkv^T + b_qkv  (M=8192, N=1536, K=512), bf16 MFMA.
// A and B pre-converted bf16 -> staging is pure 16B copies (no VALU convert).
// q (pre-scaled by 1/8), k -> [B,H,N,D]; v -> transposed [B,H,D,N].
// ---------------------------------------------------------------------------
__global__ __launch_bounds__(256) void qkv_gemm(
    const unsigned short* __restrict__ xb, const unsigned short* __restrict__ wqb,
    const float* __restrict__ bq,
    unsigned short* __restrict__ q_ws, unsigned short* __restrict__ k_ws,
    unsigned short* __restrict__ v_ws){
  __shared__ unsigned short s_a[128][40];   // +8 pad
  __shared__ unsigned short s_b[128][40];
  const int tid = threadIdx.x;
  const int bx = blockIdx.x;            // col tile 0..11
  const int by = blockIdx.y;            // row tile 0..63
  const int row0 = by * 128, n0 = bx * 128;
  const int lane = tid & 63, wv = tid >> 6;
  const int wr = wv >> 1, wc = wv & 1;
  const int lm = lane & 15, quad = lane >> 4;
  f32x4 acc[4][4] = {};
  for (int kc = 0; kc < 16; ++kc) {
    const int k0 = kc * 32;
    __syncthreads();
    #pragma unroll
    for (int i = 0; i < 2; ++i) {        // A and B: direct bf16 16B copies
      int g = tid * 2 + i;
      int r = g >> 2, c8 = (g & 3) * 8;
      *(bf16x8*)&s_a[r][c8] = *(const bf16x8*)(xb  + (size_t)(row0 + r)*512 + k0 + c8);
      *(bf16x8*)&s_b[r][c8] = *(const bf16x8*)(wqb + (size_t)(n0  + r)*512 + k0 + c8);
    }
    __syncthreads();
    bf16x8 af[4], bfr[4];
    #pragma unroll
    for (int mt = 0; mt < 4; ++mt) af[mt]  = *(const bf16x8*)&s_a[wr*64 + mt*16 + lm][quad*8];
    #pragma unroll
    for (int nt = 0; nt < 4; ++nt) bfr[nt] = *(const bf16x8*)&s_b[wc*64 + nt*16 + lm][quad*8];
    #pragma unroll
    for (int mt = 0; mt < 4; ++mt)
      #pragma unroll
      for (int nt = 0; nt < 4; ++nt)
        acc[mt][nt] = __builtin_amdgcn_mfma_f32_16x16x32_bf16(af[mt], bfr[nt], acc[mt][nt], 0, 0, 0);
  }
  #pragma unroll
  for (int nt = 0; nt < 4; ++nt) {
    int c = n0 + wc*64 + nt*16 + lm;
    float bias = bq[c];
    int sec = c >> 9, ch = c & 511, h = ch >> 6, d = ch & 63;
    #pragma unroll
    for (int mt = 0; mt < 4; ++mt) {
      #pragma unroll
      for (int r = 0; r < 4; ++r) {
        int grow = row0 + wr*64 + mt*16 + quad*4 + r;
        int b = grow >> 8, n = grow & 255;
        float val = acc[mt][nt][r] + bias;
        if (sec == 0)      q_ws[(((size_t)b*Hn + h)*Nn + n)*Dn + d] = f2bf(val * 0.125f);
        else if (sec == 1) k_ws[(((size_t)b*Hn + h)*Nn + n)*Dn + d] = f2bf(val);
        else               v_ws[(((size_t)b*Hn + h)*Dn + d)*Nn + n] = f2bf(val);
      }
    }
  }
}

// ---------------------------------------------------------------------------
// Kernel B: flash attention, ONE head per wave (round 6 had 2 -> only 2048
// waves = 2/SIMD, latency-bound at 21% VALU / 24% HBM). Grid 1024 blocks:
// blk = b(5) | qt(4) | hp(1); wave wv owns head hp*4+wv. 4096 waves = 4/SIMD.
// Online softmax; P transits per-wave LDS strip; single barrier.
// ---------------------------------------------------------------------------
__global__ __launch_bounds__(256) void attn_kernel(
    const float* __restrict__ U, const float* __restrict__ w_u, const float* __restrict__ b_u,
    const unsigned short* __restrict__ q_ws, const unsigned short* __restrict__ k_ws,
    const unsigned short* __restrict__ v_ws, unsigned short* __restrict__ o_ws){
  __shared__ unsigned short s_p[4][16][40];   // [wave][row][32+8 pad]
  __shared__ float s_wu[64];
  __shared__ float s_bu[8];
  const int tid = threadIdx.x;
  const int wv = tid >> 6, lane = tid & 63;
  const int lm = lane & 15, quad = lane >> 4;
  const int blk = blockIdx.x;
  const int b = blk >> 5;
  const int qt0 = ((blk >> 1) & 15) * 16;
  const int hp = blk & 1;
  const int h = hp * 4 + wv;
  if (tid < 64) s_wu[tid] = w_u[tid];
  if (tid < 8)  s_bu[tid] = b_u[tid];
  __syncthreads();   // only barrier
  const size_t hb = (size_t)b * Hn + h;
  float wu[8];
  #pragma unroll
  for (int i = 0; i < 8; ++i) wu[i] = s_wu[h*8 + i];
  const float bu = s_bu[h];
  // Q fragments (q pre-scaled by 1/8 in qkv_gemm)
  const unsigned short* qp = q_ws + (hb*Nn + qt0 + lm)*Dn;
  const bf16x8 qa0 = *(const bf16x8*)(qp + quad*8);
  const bf16x8 qa1 = *(const bf16x8*)(qp + 32 + quad*8);
  f32x4 oa[4] = {};
  float m[4], l[4];
  #pragma unroll
  for (int r = 0; r < 4; ++r) { m[r] = -3.0e38f; l[r] = 0.f; }
  const float* Ub = U + ((size_t)(b*Nn + qt0)) * Nn * 8;
  #pragma unroll 1
  for (int ck = 0; ck < 8; ++ck) {
    f32x4 la0, la1;
    #pragma unroll
    for (int t = 0; t < 2; ++t) {
      const int key0 = ck*32 + t*16;
      f32x4 c;
      #pragma unroll
      for (int r = 0; r < 4; ++r) {
        const float4* up = (const float4*)(Ub + ((size_t)(quad*4+r)*Nn + key0 + lm)*8);
        float4 ua = up[0], uc = up[1];
        c[r] = bu + ua.x*wu[0] + ua.y*wu[1] + ua.z*wu[2] + ua.w*wu[3]
                  + uc.x*wu[4] + uc.y*wu[5] + uc.z*wu[6] + uc.w*wu[7];
      }
      const unsigned short* kp = k_ws + (hb*Nn + key0 + lm)*Dn;
      bf16x8 kf;
      kf = *(const bf16x8*)(kp + quad*8);
      c = __builtin_amdgcn_mfma_f32_16x16x32_bf16(qa0, kf, c, 0, 0, 0);
      kf = *(const bf16x8*)(kp + 32 + quad*8);
      c = __builtin_amdgcn_mfma_f32_16x16x32_bf16(qa1, kf, c, 0, 0, 0);
      if (t == 0) la0 = c; else la1 = c;
    }
    // --- online softmax per query row (quad*4+r)
    #pragma unroll
    for (int r = 0; r < 4; ++r) {
      float tm = fmaxf(la0[r], la1[r]);
      #pragma unroll
      for (int msk = 1; msk < 16; msk <<= 1) tm = fmaxf(tm, __shfl_xor(tm, msk));
      float mn = fmaxf(m[r], tm);
      float al = __expf(m[r] - mn);
      m[r] = mn;
      float e0 = __expf(la0[r] - mn), e1 = __expf(la1[r] - mn);
      la0[r] = e0; la1[r] = e1;
      float s = e0 + e1;
      #pragma unroll
      for (int msk = 1; msk < 16; msk <<= 1) s += __shfl_xor(s, msk);
      l[r] = l[r] * al + s;
      #pragma unroll
      for (int nt = 0; nt < 4; ++nt) oa[nt][r] *= al;
    }
    // --- pack P (unnormalized bf16) C-layout -> per-wave strip
    #pragma unroll
    for (int r = 0; r < 4; ++r) {
      s_p[wv][quad*4+r][lm]      = f2bf(la0[r]);
      s_p[wv][quad*4+r][16 + lm] = f2bf(la1[r]);
    }
    // --- PV for this 32-key chunk (wave-internal, no barrier)
    const bf16x8 ap = *(const bf16x8*)&s_p[wv][lm][quad*8];
    #pragma unroll
    for (int nt = 0; nt < 4; ++nt) {
      bf16x8 bv = *(const bf16x8*)(v_ws + (hb*Dn + nt*16 + lm)*Nn + ck*32 + quad*8);
      oa[nt] = __builtin_amdgcn_mfma_f32_16x16x32_bf16(ap, bv, oa[nt], 0, 0, 0);
    }
  }
  // --- finalize
  #pragma unroll
  for (int r = 0; r < 4; ++r) {
    const float iv = 1.0f / l[r];
    const int n = qt0 + quad*4 + r;
    #pragma unroll
    for (int nt = 0; nt < 4; ++nt)
      o_ws[((size_t)(b*Nn + n))*En + h*64 + nt*16 + lm] = f2bf(oa[nt][r] * iv);
  }
}

// ---------------------------------------------------------------------------
// Kernel C: out = o @ w_out^T + b_out (M=8192, N=512, K=512), fp32 out.
// B (w_out) pre-converted bf16 -> staging is pure 16B copies.
// ---------------------------------------------------------------------------
__global__ __launch_bounds__(256) void oproj_gemm(
    const unsigned short* __restrict__ o_ws, const unsigned short* __restrict__ wob,
    const float* __restrict__ bo, float* __restrict__ out){
  __shared__ unsigned short s_a[128][40];
  __shared__ unsigned short s_b[128][40];
  const int tid = threadIdx.x;
  const int bx = blockIdx.x;            // 0..3
  const int by = blockIdx.y;            // 0..63
  const int row0 = by * 128, n0 = bx * 128;
  const int lane = tid & 63, wv = tid >> 6;
  const int wr = wv >> 1, wc = wv & 1;
  const int lm = lane & 15, quad = lane >> 4;
  f32x4 acc[4][4] = {};
  for (int kc = 0; kc < 16; ++kc) {
    const int k0 = kc * 32;
    __syncthreads();
    #pragma unroll
    for (int i = 0; i < 2; ++i) {
      int g = tid * 2 + i;
      int r = g >> 2, c8 = (g & 3) * 8;
      *(bf16x8*)&s_a[r][c8] = *(const bf16x8*)(o_ws + (size_t)(row0 + r)*512 + k0 + c8);
      *(bf16x8*)&s_b[r][c8] = *(const bf16x8*)(wob  + (size_t)(n0  + r)*512 + k0 + c8);
    }
    __syncthreads();
    bf16x8 af[4], bfr[4];
    #pragma unroll
    for (int mt = 0; mt < 4; ++mt) af[mt]  = *(const bf16x8*)&s_a[wr*64 + mt*16 + lm][quad*8];
    #pragma unroll
    for (int nt = 0; nt < 4; ++nt) bfr[nt] = *(const bf16x8*)&s_b[wc*64 + nt*16 + lm][quad*8];
    #pragma unroll
    for (int mt = 0; mt < 4; ++mt)
      #pragma unroll
      for (int nt = 0; nt < 4; ++nt)
        acc[mt][nt] = __builtin_amdgcn_mfma_f32_16x16x32_bf16(af[mt], bfr[nt], acc[mt][nt], 0, 0, 0);
  }
  #pragma unroll
  for (int nt = 0; nt < 4; ++nt) {
    int c = n0 + wc*64 + nt*16 + lm;
    float bias = bo[c];
    #pragma unroll
    for (int mt = 0; mt < 4; ++mt)
      #pragma unroll
      for (int r = 0; r < 4; ++r) {
        int grow = row0 + wr*64 + mt*16 + quad*4 + r;
        out[(size_t)grow*512 + c] = acc[mt][nt][r] + bias;
      }
  }
}

extern "C" void kernel_launch(void* const* d_in, const int* in_sizes, int n_in,
                              void* d_out, int out_size, void* d_ws, size_t ws_size,
                              hipStream_t stream) {
  const float* x     = (const float*)d_in[0];
  const float* U     = (const float*)d_in[1];
  const float* w_qkv = (const float*)d_in[2];
  const float* b_qkv = (const float*)d_in[3];
  const float* w_out = (const float*)d_in[4];
  const float* b_out = (const float*)d_in[5];
  const float* w_u   = (const float*)d_in[6];
  const float* b_u   = (const float*)d_in[7];
  float* out = (float*)d_out;

  const size_t per = (size_t)Bn * Hn * Nn * Dn;       // 4,194,304 elements
  unsigned short* q_ws = (unsigned short*)d_ws;       // ws: 32 MiB total (proven fits)
  unsigned short* k_ws = q_ws + per;
  unsigned short* v_ws = k_ws + per;                  // transposed [B,H,D,N]
  unsigned short* o_ws = v_ws + per;                  // [B,N,E]

  // d_out (16.8 MB fp32) doubles as scratch for bf16 x and w_qkv; it is fully
  // overwritten by oproj_gemm afterwards. w_out(bf16) goes into the dead q_ws
  // region after attn (q no longer needed).
  unsigned short* xb  = (unsigned short*)d_out;       // 8.39 MB
  unsigned short* wqb = xb + per;                     // 1.57 MB (1536*512)
  unsigned short* wob = q_ws;                         // 0.52 MB (512*512), post-attn

  convert_bf16<<<dim3(2048), dim3(256), 0, stream>>>(x, xb);          // 4,194,304 el
  convert_bf16<<<dim3(384),  dim3(256), 0, stream>>>(w_qkv, wqb);     //   786,432 el
  qkv_gemm   <<<dim3(12, 64), dim3(256), 0, stream>>>(xb, wqb, b_qkv, q_ws, k_ws, v_ws);
  attn_kernel<<<dim3(1024),   dim3(256), 0, stream>>>(U, w_u, b_u, q_ws, k_ws, v_ws, o_ws);
  convert_bf16<<<dim3(128),  dim3(256), 0, stream>>>(w_out, wob);     //   262,144 el
  oproj_gemm <<<dim3(4, 64),  dim3(256), 0, stream>>>(o_ws, wob, b_out, out);
}